// Round 12
// baseline (356.147 us; speedup 1.0000x reference)
//
#include <hip/hip_runtime.h>
#include <stdint.h>

#define SQL 2048
#define HID 4096
#define NHEADS 32
#define HDSZ 128
#define QKVD 4608
#define QDIM 4096

typedef unsigned short u16;
typedef __attribute__((ext_vector_type(8))) short short8;
typedef __attribute__((ext_vector_type(4))) float f32x4;

#define AS1(p) ((__attribute__((address_space(1))) void*)(p))
#define AS3(p) ((__attribute__((address_space(3))) void*)(p))

__device__ __forceinline__ float bf2f(u16 u) {
  return __uint_as_float(((uint32_t)u) << 16);
}
__device__ __forceinline__ u16 f2bf(float f) {
  uint32_t x = __float_as_uint(f);
  x += 0x7fffu + ((x >> 16) & 1u);
  return (u16)(x >> 16);
}

// ---------- fp32 -> bf16 convert, 8 elems/thread ----------
__global__ void k_cvt(const float* __restrict__ in, u16* __restrict__ out, int n8) {
  int i = blockIdx.x * blockDim.x + threadIdx.x;
  int stride = gridDim.x * blockDim.x;
  for (; i < n8; i += stride) {
    const float4* p = reinterpret_cast<const float4*>(in) + (size_t)i * 2;
    float4 a = p[0], b = p[1];
    short8 o;
    o[0] = (short)f2bf(a.x); o[1] = (short)f2bf(a.y);
    o[2] = (short)f2bf(a.z); o[3] = (short)f2bf(a.w);
    o[4] = (short)f2bf(b.x); o[5] = (short)f2bf(b.y);
    o[6] = (short)f2bf(b.z); o[7] = (short)f2bf(b.w);
    reinterpret_cast<short8*>(out)[i] = o;
  }
}

// ---------- GEMM C[M][N] = A[M][K] * B[N][K]^T, bf16 MFMA ----------
// 2-phase pipelined (T3-minimum): LDS double-buffer, STAGE(t+1) issued BEFORE
// compute(t), counted s_waitcnt vmcnt(8) (the 8 newest loads stay in flight
// across the barrier), raw s_barrier; tail barrier protects buf[cur] from
// next iteration's overwrite. XCD-aware bijective block swizzle (T1).
// MODE 0: qkv epilogue (bias + 1/sqrt(d) on q + scatter to q/k/vt).
// MODE 1: fp32 C store.
template<int MODE>
__global__ __launch_bounds__(256, 2)
void k_gemm(const u16* __restrict__ A, const u16* __restrict__ B,
            const float* __restrict__ bias,
            u16* __restrict__ qbuf, u16* __restrict__ kbuf, u16* __restrict__ vtbuf,
            float* __restrict__ outf)
{
  __shared__ __align__(16) u16 ldsA[2][128 * 64];
  __shared__ __align__(16) u16 ldsB[2][128 * 64];
  const int tid = threadIdx.x;
  const int wid = tid >> 6, lane = tid & 63;
  const int l15 = lane & 15, lg = lane >> 4;

  // XCD-aware swizzle: nwg = gridX*gridY is a multiple of 8 for both GEMMs.
  const int gridX = gridDim.x;
  const int nwg = gridX * gridDim.y;
  const int orig = blockIdx.y * gridX + blockIdx.x;
  const int cpx = nwg >> 3;
  const int swz = (orig & 7) * cpx + (orig >> 3);
  const int m0 = (swz / gridX) * 128, n0 = (swz % gridX) * 128;
  const int wr = wid >> 1, wc = wid & 1;

  f32x4 acc[4][4] = {};

  const int srow = lane >> 3;                      // row within 8-row segment
  const int skb  = (((lane & 7) ^ srow) << 4);     // pre-swizzled source byte
  const size_t rowbytes = (size_t)HID * 2;
  const int NT = HID / 64;

#define GSTAGE(t, b)                                                            \
  do {                                                                          \
    const char* Ab_ = (const char*)A + (size_t)m0 * rowbytes + (size_t)(t) * 128; \
    const char* Bb_ = (const char*)B + (size_t)n0 * rowbytes + (size_t)(t) * 128; \
    _Pragma("unroll")                                                           \
    for (int i_ = 0; i_ < 4; ++i_) {                                            \
      int seg_ = i_ * 4 + wid;                                                  \
      int row_ = seg_ * 8 + srow;                                               \
      __builtin_amdgcn_global_load_lds(AS1(Ab_ + (size_t)row_ * rowbytes + skb),\
                                       AS3(ldsA[b] + seg_ * 512), 16, 0, 0);    \
      __builtin_amdgcn_global_load_lds(AS1(Bb_ + (size_t)row_ * rowbytes + skb),\
                                       AS3(ldsB[b] + seg_ * 512), 16, 0, 0);    \
    }                                                                           \
  } while (0)

  GSTAGE(0, 0);

  for (int t = 0; t < NT; ++t) {
    const int cur = t & 1;
    if (t + 1 < NT) {
      GSTAGE(t + 1, cur ^ 1);
      asm volatile("s_waitcnt vmcnt(8)" ::: "memory");   // tile-t loads landed
    } else {
      asm volatile("s_waitcnt vmcnt(0)" ::: "memory");
    }
    __builtin_amdgcn_s_barrier();                        // all waves: t ready

#pragma unroll
    for (int kc = 0; kc < 2; ++kc) {
      short8 af[4], bfr[4];
#pragma unroll
      for (int mi = 0; mi < 4; ++mi) {
        int row = wr * 64 + mi * 16 + l15;
        int kb = (kc * 64 + lg * 16) ^ ((row & 7) << 4);
        af[mi] = *reinterpret_cast<const short8*>((const char*)ldsA[cur] + row * 128 + kb);
      }
#pragma unroll
      for (int ni = 0; ni < 4; ++ni) {
        int row = wc * 64 + ni * 16 + l15;
        int kb = (kc * 64 + lg * 16) ^ ((row & 7) << 4);
        bfr[ni] = *reinterpret_cast<const short8*>((const char*)ldsB[cur] + row * 128 + kb);
      }
      __builtin_amdgcn_s_setprio(1);
#pragma unroll
      for (int mi = 0; mi < 4; ++mi)
#pragma unroll
        for (int ni = 0; ni < 4; ++ni)
          acc[mi][ni] = __builtin_amdgcn_mfma_f32_16x16x32_bf16(af[mi], bfr[ni], acc[mi][ni], 0, 0, 0);
      __builtin_amdgcn_s_setprio(0);
    }
    asm volatile("" ::: "memory");
    __builtin_amdgcn_s_barrier();     // all waves done reading buf[cur] before
                                      // next iter's GSTAGE overwrites it
  }
#undef GSTAGE

#pragma unroll
  for (int mi = 0; mi < 4; ++mi) {
#pragma unroll
    for (int ni = 0; ni < 4; ++ni) {
      int row0 = m0 + wr * 64 + mi * 16 + lg * 4;
      int col  = n0 + wc * 64 + ni * 16 + l15;
      if (MODE == 0) {
        float bv = bias[col];
#pragma unroll
        for (int j = 0; j < 4; ++j) {
          float v = acc[mi][ni][j] + bv;
          int r = row0 + j;
          if (col < QDIM) {
            v *= 0.08838834764831845f;       // fold 1/sqrt(128) into q
            int hh = col >> 7, d = col & 127;
            qbuf[((size_t)hh * SQL + r) * HDSZ + d] = f2bf(v);
          } else if (col < QDIM + 256) {
            int c2 = col - QDIM; int g = c2 >> 7, d = c2 & 127;
            kbuf[((size_t)g * SQL + r) * HDSZ + d] = f2bf(v);
          } else {
            int c2 = col - QDIM - 256; int g = c2 >> 7, d = c2 & 127;
            vtbuf[((size_t)g * HDSZ + d) * SQL + r] = f2bf(v);   // V transposed
          }
        }
      } else {
#pragma unroll
        for (int j = 0; j < 4; ++j)
          outf[(size_t)(row0 + j) * QDIM + col] = acc[mi][ni][j];
      }
    }
  }
}

// ---------- RoPE (interleaved pairs, first 64 dims), in place on q and k ----------
__global__ void k_rope(u16* __restrict__ qbuf, u16* __restrict__ kbuf,
                       const float* __restrict__ rope) {
  int idx = blockIdx.x * blockDim.x + threadIdx.x;
  if (idx >= SQL * 34 * 32) return;
  int p = idx & 31;
  int hh = (idx >> 5) % 34;
  int s = idx / (34 * 32);
  float c  = rope[s * 64 + p * 2 + 0];
  float sn = rope[s * 64 + p * 2 + 1];
  u16* base = (hh < 32) ? (qbuf + ((size_t)hh * SQL + s) * HDSZ)
                        : (kbuf + ((size_t)(hh - 32) * SQL + s) * HDSZ);
  u16* pp = base + 2 * p;
  uint32_t packed = *reinterpret_cast<uint32_t*>(pp);
  float x0 = bf2f((u16)(packed & 0xffff));
  float x1 = bf2f((u16)(packed >> 16));
  float o0 = x0 * c - x1 * sn;
  float o1 = x1 * c + x0 * sn;
  *reinterpret_cast<uint32_t*>(pp) = (uint32_t)f2bf(o0) | ((uint32_t)f2bf(o1) << 16);
}

// ---------- flash attention: 8-wave cooperative, LDS-staged K/V ----------
// Block = 512 threads (8 waves), one head h, stripe b = blockIdx.y (0..7).
// Wave w owns q-rows [256w + 32b, +32)  -> every block has the SAME total
// causal work (perfect balance); grid = 32 heads x 8 = 256 blocks = 1/CU.
// K tile [64 kv][128 d] and V^T tile [128 d][64 kv] double-buffered in LDS,
// staged via global_load_lds(16B) with pre-swizzled source + XOR read.
// Per-wave compute = swapped-QK in-register softmax (verified R10).
__global__ __launch_bounds__(512, 2)
void k_attn(const u16* __restrict__ qbuf, const u16* __restrict__ kbuf,
            const u16* __restrict__ vtbuf, u16* __restrict__ ctx)
{
  __shared__ __align__(16) u16 KL[2][64 * 128];     // 2 x 16 KB
  __shared__ __align__(16) u16 VL[2][128 * 64];     // 2 x 16 KB
  __shared__ uint32_t plw[8][32][36];               // per-wave P transpose
  const int tid = threadIdx.x;
  const int wid = tid >> 6, lane = tid & 63;
  const int l15 = lane & 15, lg = lane >> 4;
  const int h = blockIdx.x;
  const int g = h >> 4;                     // n_rep = 16
  const int bq = blockIdx.y;                // stripe 0..7
  const int q0 = wid * 256 + bq * 32;       // this wave's q-tile
  const int ext = q0 + 32;                  // causal extent (exclusive)
  const int NT = (1824 + 32 * bq + 63) >> 6;  // tiles to stage (max ext/64)

  // staging geometry (per thread, 2 chunks of 16B per tile per buffer)
  const int cA = tid, cB = tid + 512;
  const int krA = cA >> 4, kiA = (cA & 15) ^ (krA & 7);
  const int krB = cB >> 4, kiB = (cB & 15) ^ (krB & 7);
  const int vrA = cA >> 3, viA = (cA & 7) ^ (vrA & 7);
  const int vrB = cB >> 3, viB = (cB & 7) ^ (vrB & 7);
  const char* kg = (const char*)(kbuf + (size_t)g * SQL * HDSZ);
  const char* vg = (const char*)(vtbuf + (size_t)g * HDSZ * SQL);

#define STAGE(t, b)                                                             \
  do {                                                                          \
    int j0s = (t) * 64;                                                         \
    __builtin_amdgcn_global_load_lds(AS1(kg + (size_t)(j0s + krA) * 256 + (kiA << 4)), \
                                     AS3((char*)KL[b] + cA * 16), 16, 0, 0);    \
    __builtin_amdgcn_global_load_lds(AS1(kg + (size_t)(j0s + krB) * 256 + (kiB << 4)), \
                                     AS3((char*)KL[b] + cB * 16), 16, 0, 0);    \
    __builtin_amdgcn_global_load_lds(AS1(vg + (size_t)vrA * (SQL * 2) + j0s * 2 + (viA << 4)), \
                                     AS3((char*)VL[b] + cA * 16), 16, 0, 0);    \
    __builtin_amdgcn_global_load_lds(AS1(vg + (size_t)vrB * (SQL * 2) + j0s * 2 + (viB << 4)), \
                                     AS3((char*)VL[b] + cB * 16), 16, 0, 0);    \
  } while (0)

  short8 aq[2][4];
#pragma unroll
  for (int rt = 0; rt < 2; ++rt) {
    const u16* qp = qbuf + ((size_t)h * SQL + q0 + rt * 16 + l15) * HDSZ + lg * 8;
#pragma unroll
    for (int kc = 0; kc < 4; ++kc)
      aq[rt][kc] = *reinterpret_cast<const short8*>(qp + kc * 32);
  }
  f32x4 o[2][8] = {};
  float mrow[2], lrow[2];
#pragma unroll
  for (int rt = 0; rt < 2; ++rt) { mrow[rt] = -__builtin_inff(); lrow[rt] = 0.f; }

  STAGE(0, 0);
  __syncthreads();

  for (int i = 0; i < NT; ++i) {
    const int cur = i & 1;
    if (i + 1 < NT) STAGE(i + 1, cur ^ 1);

    const int j0 = i * 64;
    if (j0 < ext) {
      const char* kb0 = (const char*)KL[cur];
      const char* vb0 = (const char*)VL[cur];
      const int swz = (l15 & 7) << 4;

      // swapped QK^T with lazy K-fragment reads
      f32x4 st[2][4] = {};
#pragma unroll
      for (int kc = 0; kc < 4; ++kc) {
        short8 bk4[4];
#pragma unroll
        for (int kt = 0; kt < 4; ++kt) {
          int r = 16 * kt + l15;
          bk4[kt] = *reinterpret_cast<const short8*>(
              kb0 + r * 256 + ((kc * 64 + lg * 16) ^ swz));
        }
        __builtin_amdgcn_s_setprio(1);
#pragma unroll
        for (int rt = 0; rt < 2; ++rt)
#pragma unroll
          for (int kt = 0; kt < 4; ++kt)
            st[rt][kt] = __builtin_amdgcn_mfma_f32_16x16x32_bf16(bk4[kt], aq[rt][kc], st[rt][kt], 0, 0, 0);
        __builtin_amdgcn_s_setprio(0);
      }

      // softmax: one q-row per l15; 4 lanes (lg) hold 16 kv values each
      const bool domask = (j0 + 63 > q0);
#pragma unroll
      for (int rt = 0; rt < 2; ++rt) {
        const int q = q0 + rt * 16 + l15;
        float p[4][4];
#pragma unroll
        for (int kt = 0; kt < 4; ++kt)
#pragma unroll
          for (int j = 0; j < 4; ++j) {
            float v = st[rt][kt][j];
            if (domask) {
              int kvi = j0 + kt * 16 + lg * 4 + j;
              v = (kvi > q) ? -1e30f : v;
            }
            p[kt][j] = v;
          }
        float rm = fmaxf(fmaxf(fmaxf(p[0][0], p[0][1]), fmaxf(p[0][2], p[0][3])),
                         fmaxf(fmaxf(p[1][0], p[1][1]), fmaxf(p[1][2], p[1][3])));
        rm = fmaxf(rm, fmaxf(fmaxf(fmaxf(p[2][0], p[2][1]), fmaxf(p[2][2], p[2][3])),
                             fmaxf(fmaxf(p[3][0], p[3][1]), fmaxf(p[3][2], p[3][3]))));
        rm = fmaxf(rm, __shfl_xor(rm, 16));
        rm = fmaxf(rm, __shfl_xor(rm, 32));
        if (!__all(rm <= mrow[rt] + 8.0f)) {        // defer-rescale (T13)
          float mn = fmaxf(mrow[rt], rm);
          float a = __expf(mrow[rt] - mn);          // first tile: exp(-inf)=0
          mrow[rt] = mn;
          lrow[rt] *= a;
          float ar[4];
#pragma unroll
          for (int j = 0; j < 4; ++j) ar[j] = __shfl(a, lg * 4 + j);
#pragma unroll
          for (int df = 0; df < 8; ++df) {
            o[rt][df][0] *= ar[0]; o[rt][df][1] *= ar[1];
            o[rt][df][2] *= ar[2]; o[rt][df][3] *= ar[3];
          }
        }
        float ps = 0.f;
#pragma unroll
        for (int kt = 0; kt < 4; ++kt)
#pragma unroll
          for (int j = 0; j < 4; ++j) {
            p[kt][j] = __expf(p[kt][j] - mrow[rt]);
            ps += p[kt][j];
          }
        ps += __shfl_xor(ps, 16);
        ps += __shfl_xor(ps, 32);
        lrow[rt] += ps;
#pragma unroll
        for (int kt = 0; kt < 4; ++kt)
#pragma unroll
          for (int u = 0; u < 2; ++u) {
            uint32_t W;
            asm("v_cvt_pk_bf16_f32 %0, %1, %2"
                : "=v"(W) : "v"(p[kt][2 * u]), "v"(p[kt][2 * u + 1]));
            plw[wid][rt * 16 + l15][8 * kt + 2 * lg + u] = W;
          }
      }
      asm volatile("s_waitcnt lgkmcnt(0)" ::: "memory");  // wave-local write->read

      short8 ap[2][2];
#pragma unroll
      for (int rt = 0; rt < 2; ++rt)
#pragma unroll
        for (int kc2 = 0; kc2 < 2; ++kc2)
          ap[rt][kc2] = *reinterpret_cast<const short8*>(&plw[wid][rt * 16 + l15][16 * kc2 + 4 * lg]);

      __builtin_amdgcn_s_setprio(1);
#pragma unroll
      for (int df = 0; df < 8; ++df) {
        short8 bv0, bv1;
        int rv = l15 + 16 * df;
#pragma unroll
        for (int kc2 = 0; kc2 < 2; ++kc2) {
          short8 bvv = *reinterpret_cast<const short8*>(
              vb0 + rv * 128 + ((kc2 * 64 + lg * 16) ^ swz));
          if (kc2 == 0) bv0 = bvv; else bv1 = bvv;
        }
#pragma unroll
        for (int rt = 0; rt < 2; ++rt) {
          f32x4 t = o[rt][df];
          t = __builtin_amdgcn_mfma_f32_16x16x32_bf16(ap[rt][0], bv0, t, 0, 0, 0);
          t = __builtin_amdgcn_mfma_f32_16x16x32_bf16(ap[rt][1], bv1, t, 0, 0, 0);
          o[rt][df] = t;
        }
      }
      __builtin_amdgcn_s_setprio(0);
    }
    __syncthreads();
  }

  // epilogue: O rows have q=q0+16rt+4lg+j; l lives at lane l15=q_local -> shfl
#pragma unroll
  for (int rt = 0; rt < 2; ++rt) {
    float linv[4];
#pragma unroll
    for (int j = 0; j < 4; ++j) linv[j] = 1.0f / __shfl(lrow[rt], lg * 4 + j);
#pragma unroll
    for (int j = 0; j < 4; ++j) {
      int row = q0 + rt * 16 + lg * 4 + j;
      u16* cp = ctx + (size_t)row * QDIM + h * HDSZ;
#pragma unroll
      for (int df = 0; df < 8; ++df)
        cp[df * 16 + l15] = f2bf(o[rt][df][j] * linv[j]);
    }
  }
#undef STAGE
}

// ---------- workspace layout (bytes) ----------
//  0        : hidden_bf16 [2048][4096]   16777216   (reused as ctx after GEMM1)
//  16777216 : W_bf16      [4608][4096]   37748736   (Wqkv, then Wdense)
//  54525952 : q           [32][2048][128] 16777216
//  71303168 : k           [2][2048][128]   1048576
//  72351744 : vt          [2][128][2048]   1048576
//  total 73400320

extern "C" void kernel_launch(void* const* d_in, const int* in_sizes, int n_in,
                              void* d_out, int out_size, void* d_ws, size_t ws_size,
                              hipStream_t stream) {
  const float* hs     = (const float*)d_in[0];
  const float* wqkv   = (const float*)d_in[1];
  const float* bqkv   = (const float*)d_in[2];
  const float* wdense = (const float*)d_in[3];
  const float* rope   = (const float*)d_in[4];
  char* ws = (char*)d_ws;
  u16* hid_b = (u16*)(ws + 0);
  u16* w_b   = (u16*)(ws + 16777216);
  u16* qb    = (u16*)(ws + 54525952);
  u16* kb    = (u16*)(ws + 71303168);
  u16* vtb   = (u16*)(ws + 72351744);
  u16* ctx   = hid_b;                      // reuse after GEMM1
  float* outf = (float*)d_out;

  k_cvt<<<2048, 256, 0, stream>>>(hs,   hid_b, SQL * HID / 8);
  k_cvt<<<2048, 256, 0, stream>>>(wqkv, w_b,   QKVD * HID / 8);
  k_gemm<0><<<dim3(QKVD / 128, SQL / 128), 256, 0, stream>>>(
      hid_b, w_b, bqkv, qb, kb, vtb, nullptr);
  k_rope<<<(SQL * 34 * 32) / 256, 256, 0, stream>>>(qb, kb, rope);
  k_cvt<<<2048, 256, 0, stream>>>(wdense, w_b, QDIM * HID / 8);   // after GEMM1
  k_attn<<<dim3(NHEADS, 8), 512, 0, stream>>>(qb, kb, vtb, ctx);
  k_gemm<1><<<dim3(QDIM / 128, SQL / 128), 256, 0, stream>>>(
      ctx, w_b, nullptr, nullptr, nullptr, nullptr, outf);
}

// Round 13
// 300.408 us; speedup vs baseline: 1.1855x; 1.1855x over previous
//
#include <hip/hip_runtime.h>
#include <stdint.h>

#define SQL 2048
#define HID 4096
#define NHEADS 32
#define HDSZ 128
#define QKVD 4608
#define QDIM 4096

typedef unsigned short u16;
typedef __attribute__((ext_vector_type(8))) short short8;
typedef __attribute__((ext_vector_type(4))) float f32x4;

#define AS1(p) ((__attribute__((address_space(1))) void*)(p))
#define AS3(p) ((__attribute__((address_space(3))) void*)(p))

__device__ __forceinline__ float bf2f(u16 u) {
  return __uint_as_float(((uint32_t)u) << 16);
}
__device__ __forceinline__ u16 f2bf(float f) {
  uint32_t x = __float_as_uint(f);
  x += 0x7fffu + ((x >> 16) & 1u);
  return (u16)(x >> 16);
}

// ---------- fp32 -> bf16 convert, 8 elems/thread ----------
__global__ void k_cvt(const float* __restrict__ in, u16* __restrict__ out, int n8) {
  int i = blockIdx.x * blockDim.x + threadIdx.x;
  int stride = gridDim.x * blockDim.x;
  for (; i < n8; i += stride) {
    const float4* p = reinterpret_cast<const float4*>(in) + (size_t)i * 2;
    float4 a = p[0], b = p[1];
    short8 o;
    o[0] = (short)f2bf(a.x); o[1] = (short)f2bf(a.y);
    o[2] = (short)f2bf(a.z); o[3] = (short)f2bf(a.w);
    o[4] = (short)f2bf(b.x); o[5] = (short)f2bf(b.y);
    o[6] = (short)f2bf(b.z); o[7] = (short)f2bf(b.w);
    reinterpret_cast<short8*>(out)[i] = o;
  }
}

// ---------- GEMM C[M][N] = A[M][K] * B[N][K]^T, bf16 MFMA ----------
// R11-verified single-buffered structure (m97 lineage): 745/666 TF here.
// MODE 0: qkv epilogue (bias + 1/sqrt(d) on q + scatter to q/k/vt).
// MODE 1: fp32 C store.
template<int MODE>
__global__ __launch_bounds__(256, 2)
void k_gemm(const u16* __restrict__ A, const u16* __restrict__ B,
            const float* __restrict__ bias,
            u16* __restrict__ qbuf, u16* __restrict__ kbuf, u16* __restrict__ vtbuf,
            float* __restrict__ outf)
{
  __shared__ __align__(16) u16 ldsA[128 * 64];
  __shared__ __align__(16) u16 ldsB[128 * 64];
  const int tid = threadIdx.x;
  const int wid = tid >> 6, lane = tid & 63;
  const int l15 = lane & 15, lg = lane >> 4;
  const int m0 = blockIdx.y * 128, n0 = blockIdx.x * 128;
  const int wr = wid >> 1, wc = wid & 1;

  f32x4 acc[4][4] = {};

  const int srow = lane >> 3;                      // row within 8-row segment
  const int skb  = (((lane & 7) ^ srow) << 4);     // pre-swizzled source byte
  const size_t rowbytes = (size_t)HID * 2;

  for (int t = 0; t < HID / 64; ++t) {
    __syncthreads();
    const char* Ab = (const char*)A + (size_t)m0 * rowbytes + (size_t)t * 128;
    const char* Bb = (const char*)B + (size_t)n0 * rowbytes + (size_t)t * 128;
#pragma unroll
    for (int i = 0; i < 4; ++i) {
      int seg = i * 4 + wid;
      int row = seg * 8 + srow;
      __builtin_amdgcn_global_load_lds(AS1(Ab + (size_t)row * rowbytes + skb),
                                       AS3(ldsA + seg * 512), 16, 0, 0);
      __builtin_amdgcn_global_load_lds(AS1(Bb + (size_t)row * rowbytes + skb),
                                       AS3(ldsB + seg * 512), 16, 0, 0);
    }
    __syncthreads();
#pragma unroll
    for (int kc = 0; kc < 2; ++kc) {
      short8 af[4], bfr[4];
#pragma unroll
      for (int mi = 0; mi < 4; ++mi) {
        int row = wr * 64 + mi * 16 + l15;
        int kb = (kc * 64 + lg * 16) ^ ((row & 7) << 4);
        af[mi] = *reinterpret_cast<const short8*>((const char*)ldsA + row * 128 + kb);
      }
#pragma unroll
      for (int ni = 0; ni < 4; ++ni) {
        int row = wc * 64 + ni * 16 + l15;
        int kb = (kc * 64 + lg * 16) ^ ((row & 7) << 4);
        bfr[ni] = *reinterpret_cast<const short8*>((const char*)ldsB + row * 128 + kb);
      }
#pragma unroll
      for (int mi = 0; mi < 4; ++mi)
#pragma unroll
        for (int ni = 0; ni < 4; ++ni)
          acc[mi][ni] = __builtin_amdgcn_mfma_f32_16x16x32_bf16(af[mi], bfr[ni], acc[mi][ni], 0, 0, 0);
    }
  }

#pragma unroll
  for (int mi = 0; mi < 4; ++mi) {
#pragma unroll
    for (int ni = 0; ni < 4; ++ni) {
      int row0 = m0 + wr * 64 + mi * 16 + lg * 4;
      int col  = n0 + wc * 64 + ni * 16 + l15;
      if (MODE == 0) {
        float bv = bias[col];
#pragma unroll
        for (int j = 0; j < 4; ++j) {
          float v = acc[mi][ni][j] + bv;
          int r = row0 + j;
          if (col < QDIM) {
            v *= 0.08838834764831845f;       // fold 1/sqrt(128) into q
            int hh = col >> 7, d = col & 127;
            qbuf[((size_t)hh * SQL + r) * HDSZ + d] = f2bf(v);
          } else if (col < QDIM + 256) {
            int c2 = col - QDIM; int g = c2 >> 7, d = c2 & 127;
            kbuf[((size_t)g * SQL + r) * HDSZ + d] = f2bf(v);
          } else {
            int c2 = col - QDIM - 256; int g = c2 >> 7, d = c2 & 127;
            vtbuf[((size_t)g * HDSZ + d) * SQL + r] = f2bf(v);   // V transposed
          }
        }
      } else {
#pragma unroll
        for (int j = 0; j < 4; ++j)
          outf[(size_t)(row0 + j) * QDIM + col] = acc[mi][ni][j];
      }
    }
  }
}

// ---------- RoPE (interleaved pairs, first 64 dims), in place on q and k ----------
__global__ void k_rope(u16* __restrict__ qbuf, u16* __restrict__ kbuf,
                       const float* __restrict__ rope) {
  int idx = blockIdx.x * blockDim.x + threadIdx.x;
  if (idx >= SQL * 34 * 32) return;
  int p = idx & 31;
  int hh = (idx >> 5) % 34;
  int s = idx / (34 * 32);
  float c  = rope[s * 64 + p * 2 + 0];
  float sn = rope[s * 64 + p * 2 + 1];
  u16* base = (hh < 32) ? (qbuf + ((size_t)hh * SQL + s) * HDSZ)
                        : (kbuf + ((size_t)(hh - 32) * SQL + s) * HDSZ);
  u16* pp = base + 2 * p;
  uint32_t packed = *reinterpret_cast<uint32_t*>(pp);
  float x0 = bf2f((u16)(packed & 0xffff));
  float x1 = bf2f((u16)(packed >> 16));
  float o0 = x0 * c - x1 * sn;
  float o1 = x1 * c + x0 * sn;
  *reinterpret_cast<uint32_t*>(pp) = (uint32_t)f2bf(o0) | ((uint32_t)f2bf(o1) << 16);
}

// ---------- flash attention: 8-wave cooperative, LDS-staged K/V ----------
// Block = 512 threads (8 waves), one head h, stripe b = blockIdx.y (0..7).
// Wave w owns q-rows [256w + 32b, +32)  -> every block has the SAME total
// causal work (perfect balance); grid = 32 heads x 8 = 256 blocks = 1/CU.
// K tile [64 kv][128 d] and V^T tile [128 d][64 kv] double-buffered in LDS,
// staged via global_load_lds(16B) with pre-swizzled source + XOR read.
// Per-wave compute = swapped-QK in-register softmax (verified R10).
__global__ __launch_bounds__(512, 2)
void k_attn(const u16* __restrict__ qbuf, const u16* __restrict__ kbuf,
            const u16* __restrict__ vtbuf, u16* __restrict__ ctx)
{
  __shared__ __align__(16) u16 KL[2][64 * 128];     // 2 x 16 KB
  __shared__ __align__(16) u16 VL[2][128 * 64];     // 2 x 16 KB
  __shared__ uint32_t plw[8][32][36];               // per-wave P transpose
  const int tid = threadIdx.x;
  const int wid = tid >> 6, lane = tid & 63;
  const int l15 = lane & 15, lg = lane >> 4;
  const int h = blockIdx.x;
  const int g = h >> 4;                     // n_rep = 16
  const int bq = blockIdx.y;                // stripe 0..7
  const int q0 = wid * 256 + bq * 32;       // this wave's q-tile
  const int ext = q0 + 32;                  // causal extent (exclusive)
  const int NT = (1824 + 32 * bq + 63) >> 6;  // tiles to stage (max ext/64)

  // staging geometry (per thread, 2 chunks of 16B per tile per buffer)
  const int cA = tid, cB = tid + 512;
  const int krA = cA >> 4, kiA = (cA & 15) ^ (krA & 7);
  const int krB = cB >> 4, kiB = (cB & 15) ^ (krB & 7);
  const int vrA = cA >> 3, viA = (cA & 7) ^ (vrA & 7);
  const int vrB = cB >> 3, viB = (cB & 7) ^ (vrB & 7);
  const char* kg = (const char*)(kbuf + (size_t)g * SQL * HDSZ);
  const char* vg = (const char*)(vtbuf + (size_t)g * HDSZ * SQL);

#define STAGE(t, b)                                                             \
  do {                                                                          \
    int j0s = (t) * 64;                                                         \
    __builtin_amdgcn_global_load_lds(AS1(kg + (size_t)(j0s + krA) * 256 + (kiA << 4)), \
                                     AS3((char*)KL[b] + cA * 16), 16, 0, 0);    \
    __builtin_amdgcn_global_load_lds(AS1(kg + (size_t)(j0s + krB) * 256 + (kiB << 4)), \
                                     AS3((char*)KL[b] + cB * 16), 16, 0, 0);    \
    __builtin_amdgcn_global_load_lds(AS1(vg + (size_t)vrA * (SQL * 2) + j0s * 2 + (viA << 4)), \
                                     AS3((char*)VL[b] + cA * 16), 16, 0, 0);    \
    __builtin_amdgcn_global_load_lds(AS1(vg + (size_t)vrB * (SQL * 2) + j0s * 2 + (viB << 4)), \
                                     AS3((char*)VL[b] + cB * 16), 16, 0, 0);    \
  } while (0)

  short8 aq[2][4];
#pragma unroll
  for (int rt = 0; rt < 2; ++rt) {
    const u16* qp = qbuf + ((size_t)h * SQL + q0 + rt * 16 + l15) * HDSZ + lg * 8;
#pragma unroll
    for (int kc = 0; kc < 4; ++kc)
      aq[rt][kc] = *reinterpret_cast<const short8*>(qp + kc * 32);
  }
  f32x4 o[2][8] = {};
  float mrow[2], lrow[2];
#pragma unroll
  for (int rt = 0; rt < 2; ++rt) { mrow[rt] = -__builtin_inff(); lrow[rt] = 0.f; }

  STAGE(0, 0);
  __syncthreads();

  for (int i = 0; i < NT; ++i) {
    const int cur = i & 1;
    if (i + 1 < NT) STAGE(i + 1, cur ^ 1);

    const int j0 = i * 64;
    if (j0 < ext) {
      const char* kb0 = (const char*)KL[cur];
      const char* vb0 = (const char*)VL[cur];
      const int swz = (l15 & 7) << 4;

      // swapped QK^T with lazy K-fragment reads
      f32x4 st[2][4] = {};
#pragma unroll
      for (int kc = 0; kc < 4; ++kc) {
        short8 bk4[4];
#pragma unroll
        for (int kt = 0; kt < 4; ++kt) {
          int r = 16 * kt + l15;
          bk4[kt] = *reinterpret_cast<const short8*>(
              kb0 + r * 256 + ((kc * 64 + lg * 16) ^ swz));
        }
        __builtin_amdgcn_s_setprio(1);
#pragma unroll
        for (int rt = 0; rt < 2; ++rt)
#pragma unroll
          for (int kt = 0; kt < 4; ++kt)
            st[rt][kt] = __builtin_amdgcn_mfma_f32_16x16x32_bf16(bk4[kt], aq[rt][kc], st[rt][kt], 0, 0, 0);
        __builtin_amdgcn_s_setprio(0);
      }

      // softmax: one q-row per l15; 4 lanes (lg) hold 16 kv values each
      const bool domask = (j0 + 63 > q0);
#pragma unroll
      for (int rt = 0; rt < 2; ++rt) {
        const int q = q0 + rt * 16 + l15;
        float p[4][4];
#pragma unroll
        for (int kt = 0; kt < 4; ++kt)
#pragma unroll
          for (int j = 0; j < 4; ++j) {
            float v = st[rt][kt][j];
            if (domask) {
              int kvi = j0 + kt * 16 + lg * 4 + j;
              v = (kvi > q) ? -1e30f : v;
            }
            p[kt][j] = v;
          }
        float rm = fmaxf(fmaxf(fmaxf(p[0][0], p[0][1]), fmaxf(p[0][2], p[0][3])),
                         fmaxf(fmaxf(p[1][0], p[1][1]), fmaxf(p[1][2], p[1][3])));
        rm = fmaxf(rm, fmaxf(fmaxf(fmaxf(p[2][0], p[2][1]), fmaxf(p[2][2], p[2][3])),
                             fmaxf(fmaxf(p[3][0], p[3][1]), fmaxf(p[3][2], p[3][3]))));
        rm = fmaxf(rm, __shfl_xor(rm, 16));
        rm = fmaxf(rm, __shfl_xor(rm, 32));
        if (!__all(rm <= mrow[rt] + 8.0f)) {        // defer-rescale (T13)
          float mn = fmaxf(mrow[rt], rm);
          float a = __expf(mrow[rt] - mn);          // first tile: exp(-inf)=0
          mrow[rt] = mn;
          lrow[rt] *= a;
          float ar[4];
#pragma unroll
          for (int j = 0; j < 4; ++j) ar[j] = __shfl(a, lg * 4 + j);
#pragma unroll
          for (int df = 0; df < 8; ++df) {
            o[rt][df][0] *= ar[0]; o[rt][df][1] *= ar[1];
            o[rt][df][2] *= ar[2]; o[rt][df][3] *= ar[3];
          }
        }
        float ps = 0.f;
#pragma unroll
        for (int kt = 0; kt < 4; ++kt)
#pragma unroll
          for (int j = 0; j < 4; ++j) {
            p[kt][j] = __expf(p[kt][j] - mrow[rt]);
            ps += p[kt][j];
          }
        ps += __shfl_xor(ps, 16);
        ps += __shfl_xor(ps, 32);
        lrow[rt] += ps;
#pragma unroll
        for (int kt = 0; kt < 4; ++kt)
#pragma unroll
          for (int u = 0; u < 2; ++u) {
            uint32_t W;
            asm("v_cvt_pk_bf16_f32 %0, %1, %2"
                : "=v"(W) : "v"(p[kt][2 * u]), "v"(p[kt][2 * u + 1]));
            plw[wid][rt * 16 + l15][8 * kt + 2 * lg + u] = W;
          }
      }
      asm volatile("s_waitcnt lgkmcnt(0)" ::: "memory");  // wave-local write->read

      short8 ap[2][2];
#pragma unroll
      for (int rt = 0; rt < 2; ++rt)
#pragma unroll
        for (int kc2 = 0; kc2 < 2; ++kc2)
          ap[rt][kc2] = *reinterpret_cast<const short8*>(&plw[wid][rt * 16 + l15][16 * kc2 + 4 * lg]);

      __builtin_amdgcn_s_setprio(1);
#pragma unroll
      for (int df = 0; df < 8; ++df) {
        short8 bv0, bv1;
        int rv = l15 + 16 * df;
#pragma unroll
        for (int kc2 = 0; kc2 < 2; ++kc2) {
          short8 bvv = *reinterpret_cast<const short8*>(
              vb0 + rv * 128 + ((kc2 * 64 + lg * 16) ^ swz));
          if (kc2 == 0) bv0 = bvv; else bv1 = bvv;
        }
#pragma unroll
        for (int rt = 0; rt < 2; ++rt) {
          f32x4 t = o[rt][df];
          t = __builtin_amdgcn_mfma_f32_16x16x32_bf16(ap[rt][0], bv0, t, 0, 0, 0);
          t = __builtin_amdgcn_mfma_f32_16x16x32_bf16(ap[rt][1], bv1, t, 0, 0, 0);
          o[rt][df] = t;
        }
      }
      __builtin_amdgcn_s_setprio(0);
    }
    __syncthreads();
  }

  // epilogue: O rows have q=q0+16rt+4lg+j; l lives at lane l15=q_local -> shfl
#pragma unroll
  for (int rt = 0; rt < 2; ++rt) {
    float linv[4];
#pragma unroll
    for (int j = 0; j < 4; ++j) linv[j] = 1.0f / __shfl(lrow[rt], lg * 4 + j);
#pragma unroll
    for (int j = 0; j < 4; ++j) {
      int row = q0 + rt * 16 + lg * 4 + j;
      u16* cp = ctx + (size_t)row * QDIM + h * HDSZ;
#pragma unroll
      for (int df = 0; df < 8; ++df)
        cp[df * 16 + l15] = f2bf(o[rt][df][j] * linv[j]);
    }
  }
#undef STAGE
}

// ---------- workspace layout (bytes) ----------
//  0        : hidden_bf16 [2048][4096]   16777216   (reused as ctx after GEMM1)
//  16777216 : W_bf16      [4608][4096]   37748736   (Wqkv, then Wdense)
//  54525952 : q           [32][2048][128] 16777216
//  71303168 : k           [2][2048][128]   1048576
//  72351744 : vt          [2][128][2048]   1048576
//  total 73400320

extern "C" void kernel_launch(void* const* d_in, const int* in_sizes, int n_in,
                              void* d_out, int out_size, void* d_ws, size_t ws_size,
                              hipStream_t stream) {
  const float* hs     = (const float*)d_in[0];
  const float* wqkv   = (const float*)d_in[1];
  const float* bqkv   = (const float*)d_in[2];
  const float* wdense = (const float*)d_in[3];
  const float* rope   = (const float*)d_in[4];
  char* ws = (char*)d_ws;
  u16* hid_b = (u16*)(ws + 0);
  u16* w_b   = (u16*)(ws + 16777216);
  u16* qb    = (u16*)(ws + 54525952);
  u16* kb    = (u16*)(ws + 71303168);
  u16* vtb   = (u16*)(ws + 72351744);
  u16* ctx   = hid_b;                      // reuse after GEMM1
  float* outf = (float*)d_out;

  k_cvt<<<2048, 256, 0, stream>>>(hs,   hid_b, SQL * HID / 8);
  k_cvt<<<2048, 256, 0, stream>>>(wqkv, w_b,   QKVD * HID / 8);
  k_gemm<0><<<dim3(QKVD / 128, SQL / 128), 256, 0, stream>>>(
      hid_b, w_b, bqkv, qb, kb, vtb, nullptr);
  k_rope<<<(SQL * 34 * 32) / 256, 256, 0, stream>>>(qb, kb, rope);
  k_cvt<<<2048, 256, 0, stream>>>(wdense, w_b, QDIM * HID / 8);   // after GEMM1
  k_attn<<<dim3(NHEADS, 8), 512, 0, stream>>>(qb, kb, vtb, ctx);
  k_gemm<1><<<dim3(QDIM / 128, SQL / 128), 256, 0, stream>>>(
      ctx, w_b, nullptr, nullptr, nullptr, nullptr, outf);
}